// Round 1
// baseline (113.961 us; speedup 1.0000x reference)
//
#include <hip/hip_runtime.h>
#include <hip/hip_bf16.h>
#include <cstdint>

#define SIGMA 0.01f

constexpr int D1 = 3072;
constexpr int D2 = 2048;
constexpr int D3 = 1024;

typedef __bf16 bf16x8 __attribute__((ext_vector_type(8)));
typedef float f32x4 __attribute__((ext_vector_type(4)));

#define GLOAD16(gp, lp) \
  __builtin_amdgcn_global_load_lds((const __attribute__((address_space(1))) void*)(gp), \
                                   (__attribute__((address_space(3))) void*)(lp), 16, 0, 0)

// ---------- K1: bias add + 2x2 avgpool + per-batch sum(pooled^2) ----------
__global__ void pool_kernel(const float* __restrict__ x, const float* __restrict__ bias,
                            float* __restrict__ pooled, float* __restrict__ Ssum) {
  int idx = blockIdx.x * 256 + threadIdx.x;   // [0, 4*3072)
  int b = idx / D1;
  int r = idx % D1;
  int c = r >> 10;          // 1024 = 32*32
  int oh = (r >> 5) & 31;
  int ow = r & 31;
  int xb = ((b * 3 + c) * 64 + oh * 2) * 64 + ow * 2;
  int bb = (c * 64 + oh * 2) * 64 + ow * 2;
  float v = 0.25f * ((x[xb] + bias[bb]) + (x[xb + 1] + bias[bb + 1]) +
                     (x[xb + 64] + bias[bb + 64]) + (x[xb + 65] + bias[bb + 65]));
  pooled[idx] = v;
  float s = v * v;
  #pragma unroll
  for (int off = 32; off; off >>= 1) s += __shfl_down(s, off, 64);
  __shared__ float wsum[4];
  if ((threadIdx.x & 63) == 0) wsum[threadIdx.x >> 6] = s;
  __syncthreads();
  if (threadIdx.x == 0) atomicAdd(&Ssum[b], wsum[0] + wsum[1] + wsum[2] + wsum[3]);
}

// ---------- K2: mu = pooled @ W1^T  +  P1 = c1 * sum |W1| * pooled^2 ----------
__global__ void lin1_kernel(const float* __restrict__ pooled, const float* __restrict__ W1,
                            const float* __restrict__ g1p, float* __restrict__ mu,
                            float* __restrict__ Pacc) {
  int o = blockIdx.x, tid = threadIdx.x;
  const float4* wrow = (const float4*)(W1 + (size_t)o * D1);
  const float4* p4 = (const float4*)pooled;
  float acc[4] = {0, 0, 0, 0}, pab[4] = {0, 0, 0, 0};
  #pragma unroll
  for (int it = 0; it < 3; it++) {
    int i4 = tid + it * 256;
    float4 w = wrow[i4];
    float ax = fabsf(w.x), ay = fabsf(w.y), az = fabsf(w.z), aw2 = fabsf(w.w);
    #pragma unroll
    for (int b = 0; b < 4; b++) {
      float4 p = p4[b * 768 + i4];
      acc[b] += w.x * p.x + w.y * p.y + w.z * p.z + w.w * p.w;
      pab[b] += ax * p.x * p.x + ay * p.y * p.y + az * p.z * p.z + aw2 * p.w * p.w;
    }
  }
  __shared__ float red[8][4];
  #pragma unroll
  for (int v = 0; v < 8; v++) {
    float s = (v < 4) ? acc[v] : pab[v - 4];
    #pragma unroll
    for (int off = 32; off; off >>= 1) s += __shfl_down(s, off, 64);
    if ((tid & 63) == 0) red[v][tid >> 6] = s;
  }
  __syncthreads();
  if (tid < 8) {
    float s = red[tid][0] + red[tid][1] + red[tid][2] + red[tid][3];
    if (tid < 4) mu[tid * D2 + o] = s;
    else atomicAdd(&Pacc[tid - 4], g1p[0] * s);
  }
}

// ---------- K3: d=sigmoid(mu), musp=softplus(mu), m2b, dscale=sqrt(vn1)*d, Tsum ----------
__global__ void act_kernel(const float* __restrict__ mu, const float* __restrict__ Ssum,
                           const float* __restrict__ g1p, float* __restrict__ musp,
                           float* __restrict__ dscale, float* __restrict__ m2b,
                           float* __restrict__ Tsum) {
  int b = blockIdx.x, tid = threadIdx.x;
  float c1 = g1p[0];
  float vn1 = 2.0f * (SIGMA / c1) * (SIGMA / c1) * Ssum[b];
  float sv = sqrtf(vn1);
  float ts = 0.f;
  for (int j = tid; j < D2; j += 256) {
    float m = mu[b * D2 + j];
    float d = 1.0f / (1.0f + expf(-m));
    float sp = fmaxf(m, 0.f) + log1pf(expf(-fabsf(m)));
    float mm = sp * sp + vn1 * d * d;
    musp[b * D2 + j] = sp;
    dscale[b * D2 + j] = sv * d;
    m2b[b * D2 + j] = mm;
    ts += mm;
  }
  #pragma unroll
  for (int off = 32; off; off >>= 1) ts += __shfl_down(ts, off, 64);
  __shared__ float wsum[4];
  if ((tid & 63) == 0) wsum[tid >> 6] = ts;
  __syncthreads();
  if (tid == 0) Tsum[b] = wsum[0] + wsum[1] + wsum[2] + wsum[3];
}

// ---------- K4: E[b][o][j] = bf16(W2[o,j]*dscale[b,j]); mu2 = musp @ W2^T; P2 ----------
__global__ void lin2_prep_kernel(const float* __restrict__ W2, const float* __restrict__ musp,
                                 const float* __restrict__ dscale, const float* __restrict__ m2b,
                                 const float* __restrict__ g2p, __bf16* __restrict__ E,
                                 float* __restrict__ mu2, float* __restrict__ Pacc) {
  int o = blockIdx.x, tid = threadIdx.x;
  const float* wrow = W2 + (size_t)o * D2;
  int j0 = tid * 8;
  float w[8];
  *(float4*)&w[0] = *(const float4*)(wrow + j0);
  *(float4*)&w[4] = *(const float4*)(wrow + j0 + 4);
  float acc[4], pab[4];
  #pragma unroll
  for (int b = 0; b < 4; b++) {
    const float* ms = musp + b * D2 + j0;
    const float* dsc = dscale + b * D2 + j0;
    const float* mb = m2b + b * D2 + j0;
    bf16x8 ev;
    float a = 0.f, p = 0.f;
    #pragma unroll
    for (int jj = 0; jj < 8; jj++) {
      ev[jj] = (__bf16)(w[jj] * dsc[jj]);
      a += w[jj] * ms[jj];
      p += fabsf(w[jj]) * mb[jj];
    }
    *(bf16x8*)(E + ((size_t)b * D3 + o) * D2 + j0) = ev;
    acc[b] = a;
    pab[b] = p;
  }
  __shared__ float red[8][4];
  #pragma unroll
  for (int v = 0; v < 8; v++) {
    float s = (v < 4) ? acc[v] : pab[v - 4];
    #pragma unroll
    for (int off = 32; off; off >>= 1) s += __shfl_down(s, off, 64);
    if ((tid & 63) == 0) red[v][tid >> 6] = s;
  }
  __syncthreads();
  if (tid < 8) {
    float s = red[tid][0] + red[tid][1] + red[tid][2] + red[tid][3];
    if (tid < 4) mu2[tid * D3 + o] = s;
    else atomicAdd(&Pacc[tid - 4], g2p[0] * s);
  }
}

// ---------- K5: gamma2[b] = E_b @ E_b^T + vn2[b]*I  (bf16 MFMA, 128x128 tile) ----------
__global__ __launch_bounds__(256) void gamma2_gemm(const __bf16* __restrict__ E,
                                                   const float* __restrict__ Tsum,
                                                   const float* __restrict__ g2p,
                                                   float* __restrict__ gamma2) {
  // XCD-aware decode: xcd = bid&7 gets a fixed (batch, tm-half) -> A/B panels stay in one L2
  int bid = blockIdx.x;
  int xcd = bid & 7, r = bid >> 3;
  int b = xcd >> 1;
  int tm = ((xcd & 1) << 2) | (r >> 3);
  int tn = r & 7;

  __shared__ __bf16 As[128 * 32];
  __shared__ __bf16 Bs[128 * 32];

  int tid = threadIdx.x;
  int wid = tid >> 6, lane = tid & 63;
  int wr = wid >> 1, wc = wid & 1;

  const __bf16* Eb = E + (size_t)b * D3 * D2;
  int srow = tid >> 2;                    // 0..63
  int skg = tid & 3;                      // 16B chunk within 32-wide K
  const __bf16* gA = Eb + (size_t)(tm * 128 + srow) * D2 + skg * 8;
  const __bf16* gB = Eb + (size_t)(tn * 128 + srow) * D2 + skg * 8;
  char* AsB = (char*)As;
  char* BsB = (char*)Bs;
  unsigned wbase = (unsigned)wid * 1024u; // lane*16 added by HW

  f32x4 acc[4][4] = {};

  int fr = lane & 15;
  int kg = lane >> 4;
  unsigned a_off = (unsigned)((wr * 64 + fr) * 64 + kg * 16);
  unsigned b_off = (unsigned)((wc * 64 + fr) * 64 + kg * 16);

  for (int k0 = 0; k0 < D2; k0 += 32) {
    GLOAD16(gA + k0,            AsB + wbase);
    GLOAD16(gA + k0 + 64 * D2,  AsB + 4096 + wbase);
    GLOAD16(gB + k0,            BsB + wbase);
    GLOAD16(gB + k0 + 64 * D2,  BsB + 4096 + wbase);
    __syncthreads();   // drains vmcnt before reads

    bf16x8 af[4], bfv[4];
    #pragma unroll
    for (int i = 0; i < 4; i++) {
      af[i]  = *(const bf16x8*)(AsB + a_off + i * 16 * 64);
      bfv[i] = *(const bf16x8*)(BsB + b_off + i * 16 * 64);
    }
    #pragma unroll
    for (int mi = 0; mi < 4; mi++)
      #pragma unroll
      for (int ni = 0; ni < 4; ni++)
        acc[mi][ni] = __builtin_amdgcn_mfma_f32_16x16x32_bf16(af[mi], bfv[ni], acc[mi][ni], 0, 0, 0);
    __syncthreads();
  }

  float c2 = g2p[0];
  float vn2 = 2.0f * (SIGMA / c2) * (SIGMA / c2) * Tsum[b];
  float* outb = gamma2 + (size_t)b * D3 * D3;
  int col0 = tn * 128 + wc * 64 + (lane & 15);
  int row0 = tm * 128 + wr * 64 + (lane >> 4) * 4;
  #pragma unroll
  for (int mi = 0; mi < 4; mi++)
    #pragma unroll
    for (int ni = 0; ni < 4; ni++)
      #pragma unroll
      for (int rg = 0; rg < 4; rg++) {
        int row = row0 + mi * 16 + rg;
        int cc = col0 + ni * 16;
        float v = acc[mi][ni][rg];
        if (row == cc) v += vn2;
        outb[(size_t)row * D3 + cc] = v;
      }
}

// ---------- K6: copy P_tot ----------
__global__ void finalize_kernel(const float* __restrict__ Pacc, float* __restrict__ dst) {
  if (threadIdx.x < 4) dst[threadIdx.x] = Pacc[threadIdx.x];
}

extern "C" void kernel_launch(void* const* d_in, const int* in_sizes, int n_in,
                              void* d_out, int out_size, void* d_ws, size_t ws_size,
                              hipStream_t stream) {
  (void)in_sizes; (void)n_in; (void)out_size; (void)ws_size;
  const float* x    = (const float*)d_in[0];
  const float* bias = (const float*)d_in[1];
  const float* W1   = (const float*)d_in[2];
  const float* W2   = (const float*)d_in[3];
  const float* g1   = (const float*)d_in[4];
  const float* g2   = (const float*)d_in[5];
  float* out = (float*)d_out;

  float* ws     = (float*)d_ws;
  float* pooled = ws;                    // 4*3072
  float* mu     = pooled + 4 * D1;       // 4*2048
  float* musp   = mu + 4 * D2;           // 4*2048
  float* dscale = musp + 4 * D2;         // 4*2048
  float* m2b    = dscale + 4 * D2;       // 4*2048
  float* Ssum   = m2b + 4 * D2;          // 4
  float* Tsum   = Ssum + 4;              // 4
  float* Pacc   = Tsum + 4;              // 4
  size_t eoff = (size_t)(((4 * D1 + 4 * 4 * D2 + 12) * 4 + 255) / 256) * 256;
  __bf16* E = (__bf16*)((char*)d_ws + eoff);   // 4*1024*2048 bf16 = 16 MiB

  hipMemsetAsync(Ssum, 0, 12 * sizeof(float), stream);
  pool_kernel<<<48, 256, 0, stream>>>(x, bias, pooled, Ssum);
  lin1_kernel<<<2048, 256, 0, stream>>>(pooled, W1, g1, mu, Pacc);
  act_kernel<<<4, 256, 0, stream>>>(mu, Ssum, g1, musp, dscale, m2b, Tsum);
  lin2_prep_kernel<<<1024, 256, 0, stream>>>(W2, musp, dscale, m2b, g2, E, out, Pacc);
  gamma2_gemm<<<256, 256, 0, stream>>>(E, Tsum, g2, out + 4 * D3);
  finalize_kernel<<<1, 64, 0, stream>>>(Pacc, out + 4 * D3 + (size_t)4 * D3 * D3);
}

// Round 2
// 60.317 us; speedup vs baseline: 1.8894x; 1.8894x over previous
//
#include <hip/hip_runtime.h>
#include <hip/hip_bf16.h>
#include <cstdint>

#define SIGMA 0.01f

constexpr int D1 = 3072;
constexpr int D2 = 2048;
constexpr int D3 = 1024;

typedef __bf16 bf16x8 __attribute__((ext_vector_type(8)));
typedef float f32x4 __attribute__((ext_vector_type(4)));

#define GLOAD16(gp, lp) \
  __builtin_amdgcn_global_load_lds((const __attribute__((address_space(1))) void*)(gp), \
                                   (__attribute__((address_space(3))) void*)(lp), 16, 0, 0)

// ---------- K1: bias add + 2x2 avgpool + per-block partial sum(pooled^2) ----------
__global__ void pool_kernel(const float* __restrict__ x, const float* __restrict__ bias,
                            float* __restrict__ pooled, float* __restrict__ Spart) {
  int idx = blockIdx.x * 256 + threadIdx.x;   // [0, 4*3072)
  int b = idx / D1;
  int r = idx % D1;
  int c = r >> 10;
  int oh = (r >> 5) & 31;
  int ow = r & 31;
  int xb = ((b * 3 + c) * 64 + oh * 2) * 64 + ow * 2;
  int bb = (c * 64 + oh * 2) * 64 + ow * 2;
  float v = 0.25f * ((x[xb] + bias[bb]) + (x[xb + 1] + bias[bb + 1]) +
                     (x[xb + 64] + bias[bb + 64]) + (x[xb + 65] + bias[bb + 65]));
  pooled[idx] = v;
  float s = v * v;
  #pragma unroll
  for (int off = 32; off; off >>= 1) s += __shfl_down(s, off, 64);
  __shared__ float wsum[4];
  if ((threadIdx.x & 63) == 0) wsum[threadIdx.x >> 6] = s;
  __syncthreads();
  if (threadIdx.x == 0) Spart[blockIdx.x] = wsum[0] + wsum[1] + wsum[2] + wsum[3];
}

// ---------- K2: mu = pooled @ W1^T ; Pp1[b][o] = sum_i |W1[o,i]| pooled[b,i]^2 ----------
__global__ void lin1_kernel(const float* __restrict__ pooled, const float* __restrict__ W1,
                            float* __restrict__ mu, float* __restrict__ Pp1) {
  int o = blockIdx.x, tid = threadIdx.x;
  const float4* wrow = (const float4*)(W1 + (size_t)o * D1);
  const float4* p4 = (const float4*)pooled;
  float acc[4] = {0, 0, 0, 0}, pab[4] = {0, 0, 0, 0};
  #pragma unroll
  for (int it = 0; it < 3; it++) {
    int i4 = tid + it * 256;
    float4 w = wrow[i4];
    float ax = fabsf(w.x), ay = fabsf(w.y), az = fabsf(w.z), aw2 = fabsf(w.w);
    #pragma unroll
    for (int b = 0; b < 4; b++) {
      float4 p = p4[b * 768 + i4];
      acc[b] += w.x * p.x + w.y * p.y + w.z * p.z + w.w * p.w;
      pab[b] += ax * p.x * p.x + ay * p.y * p.y + az * p.z * p.z + aw2 * p.w * p.w;
    }
  }
  __shared__ float red[8][4];
  #pragma unroll
  for (int v = 0; v < 8; v++) {
    float s = (v < 4) ? acc[v] : pab[v - 4];
    #pragma unroll
    for (int off = 32; off; off >>= 1) s += __shfl_down(s, off, 64);
    if ((tid & 63) == 0) red[v][tid >> 6] = s;
  }
  __syncthreads();
  if (tid < 8) {
    float s = red[tid][0] + red[tid][1] + red[tid][2] + red[tid][3];
    if (tid < 4) mu[tid * D2 + o] = s;
    else Pp1[(size_t)(tid - 4) * D2 + o] = s;
  }
}

// ---------- K3: activation moments + per-quarter Tsum/P1 partials ----------
__global__ void act_kernel(const float* __restrict__ mu, const float* __restrict__ Spart,
                           const float* __restrict__ Pp1, const float* __restrict__ g1p,
                           float* __restrict__ musp, float* __restrict__ dscale,
                           float* __restrict__ m2b, float* __restrict__ Tpart,
                           float* __restrict__ P1q) {
  int bid = blockIdx.x, tid = threadIdx.x;
  int b = bid >> 2, q = bid & 3;
  float c1 = g1p[0];
  float sp0 = (tid < 12) ? Spart[b * 12 + tid] : 0.f;
  #pragma unroll
  for (int off = 32; off; off >>= 1) sp0 += __shfl_down(sp0, off, 64);
  __shared__ float ssb;
  if (tid == 0) ssb = sp0;
  __syncthreads();
  float vn1 = 2.0f * (SIGMA / c1) * (SIGMA / c1) * ssb;
  float sv = sqrtf(vn1);
  float ts = 0.f, ps = 0.f;
  #pragma unroll
  for (int it = 0; it < 2; it++) {
    int j = q * 512 + it * 256 + tid;
    int gj = b * D2 + j;
    float m = mu[gj];
    float d = 1.0f / (1.0f + expf(-m));
    float sp = fmaxf(m, 0.f) + log1pf(expf(-fabsf(m)));
    float mm = sp * sp + vn1 * d * d;
    musp[gj] = sp;
    dscale[gj] = sv * d;
    m2b[gj] = mm;
    ts += mm;
    ps += Pp1[gj];
  }
  __shared__ float red[2][4];
  #pragma unroll
  for (int v = 0; v < 2; v++) {
    float s = (v == 0) ? ts : ps;
    #pragma unroll
    for (int off = 32; off; off >>= 1) s += __shfl_down(s, off, 64);
    if ((tid & 63) == 0) red[v][tid >> 6] = s;
  }
  __syncthreads();
  if (tid == 0) {
    Tpart[bid] = red[0][0] + red[0][1] + red[0][2] + red[0][3];
    P1q[bid] = c1 * (red[1][0] + red[1][1] + red[1][2] + red[1][3]);
  }
}

// ---------- K4: E = bf16(W2 * dscale); mu2 = musp @ W2^T; Pp2 partials ----------
__global__ void lin2_prep_kernel(const float* __restrict__ W2, const float* __restrict__ musp,
                                 const float* __restrict__ dscale, const float* __restrict__ m2b,
                                 __bf16* __restrict__ E, float* __restrict__ mu2,
                                 float* __restrict__ Pp2) {
  int o = blockIdx.x, tid = threadIdx.x;
  const float* wrow = W2 + (size_t)o * D2;
  int j0 = tid * 8;
  float w[8];
  *(float4*)&w[0] = *(const float4*)(wrow + j0);
  *(float4*)&w[4] = *(const float4*)(wrow + j0 + 4);
  float acc[4], pab[4];
  #pragma unroll
  for (int b = 0; b < 4; b++) {
    const float* ms = musp + b * D2 + j0;
    const float* dsc = dscale + b * D2 + j0;
    const float* mb = m2b + b * D2 + j0;
    bf16x8 ev;
    float a = 0.f, p = 0.f;
    #pragma unroll
    for (int jj = 0; jj < 8; jj++) {
      ev[jj] = (__bf16)(w[jj] * dsc[jj]);
      a += w[jj] * ms[jj];
      p += fabsf(w[jj]) * mb[jj];
    }
    *(bf16x8*)(E + ((size_t)b * D3 + o) * D2 + j0) = ev;
    acc[b] = a;
    pab[b] = p;
  }
  __shared__ float red[8][4];
  #pragma unroll
  for (int v = 0; v < 8; v++) {
    float s = (v < 4) ? acc[v] : pab[v - 4];
    #pragma unroll
    for (int off = 32; off; off >>= 1) s += __shfl_down(s, off, 64);
    if ((tid & 63) == 0) red[v][tid >> 6] = s;
  }
  __syncthreads();
  if (tid < 8) {
    float s = red[tid][0] + red[tid][1] + red[tid][2] + red[tid][3];
    if (tid < 4) mu2[tid * D3 + o] = s;
    else Pp2[(size_t)(tid - 4) * D3 + o] = s;
  }
}

// ---------- K5: gamma2[b] = E_b E_b^T + vn2 I  (64x64 tiles, 1024 blocks, BK=64) ----------
__global__ __launch_bounds__(256, 4) void gamma2_gemm(const __bf16* __restrict__ E,
                                                      const float* __restrict__ Tpart,
                                                      const float* __restrict__ P1q,
                                                      const float* __restrict__ Pp2,
                                                      const float* __restrict__ g2p,
                                                      float* __restrict__ gamma2,
                                                      float* __restrict__ Ptot) {
  int bid = blockIdx.x;
  int tid = threadIdx.x;
  int wid = tid >> 6, lane = tid & 63;
  float c2 = g2p[0];

  // Block 0 also finalizes P_tot (inputs ready: lin2_prep/act completed).
  if (bid == 0) {
    float s = 0.f;
    for (int k = lane; k < D3; k += 64) s += Pp2[(size_t)wid * D3 + k];
    #pragma unroll
    for (int off = 32; off; off >>= 1) s += __shfl_down(s, off, 64);
    if (lane == 0) {
      float p1 = P1q[wid * 4] + P1q[wid * 4 + 1] + P1q[wid * 4 + 2] + P1q[wid * 4 + 3];
      Ptot[wid] = p1 + c2 * s;
    }
  }

  // XCD-aware decode: 1024 blocks, 8 XCDs -> batch pinned to an XCD pair
  int xcd = bid & 7, r = bid >> 3;
  int b = xcd >> 1;
  int tm = ((xcd & 1) << 3) | (r & 7);   // 0..15
  int tn = r >> 3;                        // 0..15
  float vn2 = 2.0f * (SIGMA / c2) * (SIGMA / c2) *
              (Tpart[b * 4] + Tpart[b * 4 + 1] + Tpart[b * 4 + 2] + Tpart[b * 4 + 3]);

  __shared__ __bf16 As[4096];  // 64 rows x 64 k, chunk-major swizzled, 8 KB
  __shared__ __bf16 Bs[4096];
  char* AsB = (char*)As;
  char* BsB = (char*)Bs;

  int wr = wid >> 1, wc = wid & 1;
  // staging source swizzle: slot s=tid (pass0) holds (row, kchunk):
  //   row = (s>>7)*16 + ((s>>2)&15), c = ((s>>6)&1)*4 + (s&3)
  int srow = ((tid >> 7) << 4) | ((tid >> 2) & 15);
  int sc = (((tid >> 6) & 1) << 2) | (tid & 3);
  const __bf16* Eb = E + (size_t)b * D3 * D2;
  const __bf16* gA = Eb + (size_t)(tm * 64 + srow) * D2 + sc * 8;
  const __bf16* gB = Eb + (size_t)(tn * 64 + srow) * D2 + sc * 8;
  unsigned dst0 = (unsigned)wid * 1024u;   // HW adds lane*16

  // fragment read: lane (fr,kg) reads slot (row&15)*4 + (c&3) within [rowblock][ksub] region
  int fr = lane & 15, kg = lane >> 4;
  unsigned po = ((unsigned)(fr << 2) | (unsigned)kg) << 4;
  unsigned a0off = (unsigned)((wr * 2 + 0) << 11) + po;
  unsigned a1off = (unsigned)((wr * 2 + 1) << 11) + po;
  unsigned b0off = (unsigned)((wc * 2 + 0) << 11) + po;
  unsigned b1off = (unsigned)((wc * 2 + 1) << 11) + po;

  f32x4 acc[2][2] = {};

  for (int k0 = 0; k0 < D2; k0 += 64) {
    GLOAD16(gA + k0,           AsB + dst0);
    GLOAD16(gA + k0 + 32 * D2, AsB + 4096 + dst0);
    GLOAD16(gB + k0,           BsB + dst0);
    GLOAD16(gB + k0 + 32 * D2, BsB + 4096 + dst0);
    __syncthreads();
    #pragma unroll
    for (int ks = 0; ks < 2; ks++) {
      unsigned kso = (unsigned)ks << 10;
      bf16x8 a0 = *(const bf16x8*)(AsB + a0off + kso);
      bf16x8 a1 = *(const bf16x8*)(AsB + a1off + kso);
      bf16x8 b0 = *(const bf16x8*)(BsB + b0off + kso);
      bf16x8 b1 = *(const bf16x8*)(BsB + b1off + kso);
      acc[0][0] = __builtin_amdgcn_mfma_f32_16x16x32_bf16(a0, b0, acc[0][0], 0, 0, 0);
      acc[0][1] = __builtin_amdgcn_mfma_f32_16x16x32_bf16(a0, b1, acc[0][1], 0, 0, 0);
      acc[1][0] = __builtin_amdgcn_mfma_f32_16x16x32_bf16(a1, b0, acc[1][0], 0, 0, 0);
      acc[1][1] = __builtin_amdgcn_mfma_f32_16x16x32_bf16(a1, b1, acc[1][1], 0, 0, 0);
    }
    __syncthreads();
  }

  float* outb = gamma2 + (size_t)b * D3 * D3;
  int row0 = tm * 64 + wr * 32 + kg * 4;
  int col0 = tn * 64 + wc * 32 + fr;
  #pragma unroll
  for (int mi = 0; mi < 2; mi++)
    #pragma unroll
    for (int ni = 0; ni < 2; ni++)
      #pragma unroll
      for (int rg = 0; rg < 4; rg++) {
        int row = row0 + mi * 16 + rg;
        int cc = col0 + ni * 16;
        float v = acc[mi][ni][rg];
        if (row == cc) v += vn2;
        outb[(size_t)row * D3 + cc] = v;
      }
}

extern "C" void kernel_launch(void* const* d_in, const int* in_sizes, int n_in,
                              void* d_out, int out_size, void* d_ws, size_t ws_size,
                              hipStream_t stream) {
  (void)in_sizes; (void)n_in; (void)out_size; (void)ws_size;
  const float* x    = (const float*)d_in[0];
  const float* bias = (const float*)d_in[1];
  const float* W1   = (const float*)d_in[2];
  const float* W2   = (const float*)d_in[3];
  const float* g1   = (const float*)d_in[4];
  const float* g2   = (const float*)d_in[5];
  float* out = (float*)d_out;

  float* ws     = (float*)d_ws;
  float* pooled = ws;                    // 4*3072 = 12288
  float* mu     = pooled + 4 * D1;       // 4*2048
  float* musp   = mu + 4 * D2;           // 4*2048
  float* dscale = musp + 4 * D2;         // 4*2048
  float* m2b    = dscale + 4 * D2;       // 4*2048
  float* Pp1    = m2b + 4 * D2;          // 4*2048
  float* Pp2    = Pp1 + 4 * D2;          // 4*1024
  float* Spart  = Pp2 + 4 * D3;          // 48
  float* Tpart  = Spart + 48;            // 16
  float* P1q    = Tpart + 16;            // 16
  size_t used = (size_t)(4 * D1 + 6 * 4 * D2 + 4 * D3 + 80) * 4;
  size_t eoff = (used + 255) / 256 * 256;
  __bf16* E = (__bf16*)((char*)d_ws + eoff);   // 4*1024*2048 bf16 = 16 MiB

  pool_kernel<<<48, 256, 0, stream>>>(x, bias, pooled, Spart);
  lin1_kernel<<<2048, 256, 0, stream>>>(pooled, W1, mu, Pp1);
  act_kernel<<<16, 256, 0, stream>>>(mu, Spart, Pp1, g1, musp, dscale, m2b, Tpart, P1q);
  lin2_prep_kernel<<<1024, 256, 0, stream>>>(W2, musp, dscale, m2b, E, out, Pp2);
  gamma2_gemm<<<1024, 256, 0, stream>>>(E, Tpart, P1q, Pp2, g2, out + 4 * D3,
                                        out + 4 * D3 + (size_t)4 * D3 * D3);
}